// Round 7
// baseline (562.249 us; speedup 1.0000x reference)
//
#include <hip/hip_runtime.h>
#include <hip/hip_cooperative_groups.h>
#include <math.h>

namespace cg = cooperative_groups;

constexpr int B_ = 4, L_ = 2048, DIN = 80, D_ = 128, H_ = 16, DH = 8;
constexpr int T_ = B_ * L_;
constexpr int LDX = T_;              // col-major activations act[chan][token]
constexpr int BHL = B_ * H_ * L_;    // 131072

// ---- static device globals ----
__device__ float g_xT  [DIN * T_];
__device__ float g_posT[D_ * L_];
__device__ float g_h   [D_ * T_];
__device__ float g_qkv [3 * D_ * T_];       // col-major [384][8192]
__device__ float g_ctx [D_ * T_];
__device__ float g_f1  [D_ * T_];
__device__ float g_pA  [2 * 8 * BHL];
__device__ float g_pl  [2 * BHL];
__device__ float g_WconvT[DIN * D_];
__device__ float g_WqkvT [D_ * 3 * D_];
__device__ float g_Wf1T  [D_ * D_];         // fused (W1*Wo)^T
__device__ float g_WfcT  [D_ * D_];         // fused (Wfc*W2)^T, cols>=80 zero
__device__ float g_bf1   [D_];
__device__ float g_bfc   [D_];

struct Params {
    const float *x, *conv_w, *conv_b, *bn_g, *bn_b, *bn_rm, *bn_rv;
    const float *in_proj_w, *in_proj_b, *out_w, *out_b;
    const float *ff_w1, *ff_b1, *ff_w2, *ff_b2, *fc_w, *fc_b;
    float* out;
};

// ---------------------------------------------------------------------------
// prep units (1000 total): 0-127 xT transpose | 128-639 posenc | 640-679 convT
// | 680-871 qkvT | 872-935 fold1 | 936-999 fold2. Block-uniform u.
// ---------------------------------------------------------------------------
__device__ void prep_unit(int u, int tid, const Params& p, float* smem) {
    if (u < 128) {                              // x [8192][80] -> xT [80][8192]
        int t0 = u * 64;
        for (int i = tid; i < 64 * 80; i += 256) {
            int t = i / 80, k = i - t * 80;
            smem[k * 65 + t] = p.x[(size_t)t0 * 80 + i];
        }
        __syncthreads();
        for (int i = tid; i < 80 * 64; i += 256) {
            int k = i >> 6, tt = i & 63;
            g_xT[(size_t)k * T_ + t0 + tt] = smem[k * 65 + tt];
        }
    } else if (u < 640) {                       // posenc fp32
        int idx = (u - 128) * 256 + tid;
        int l = idx >> 6, j = idx & 63;
        float inv = __expf((float)j * (-9.210340371976184f / 128.0f));
        float ang = (float)l * inv;
        g_posT[(2 * j) * L_ + l]     = sinf(ang);
        g_posT[(2 * j + 1) * L_ + l] = cosf(ang);
    } else if (u < 680) {                       // conv_w -> [80][128]
        int e = (u - 640) * 256 + tid;
        int o = e / 80, k = e - o * 80;
        g_WconvT[k * D_ + o] = p.conv_w[e];
    } else if (u < 872) {                       // in_proj_w -> [128][384]
        int e = (u - 680) * 256 + tid;
        int o = e >> 7, k = e & 127;
        g_WqkvT[k * (3 * D_) + o] = p.in_proj_w[e];
    } else if (u < 936) {                       // fold1: M1=W1*Wo, b1'=W1*bo+b1
        float* rowbuf = smem; float* red = smem + 256;
        int sub = tid >> 7, k = tid & 127;
        int f = (u - 872) * 2 + sub;
        rowbuf[sub * 128 + k] = p.ff_w1[f * 128 + k];
        __syncthreads();
        float acc = 0.f;
#pragma unroll 8
        for (int o = 0; o < 128; o++)
            acc = fmaf(rowbuf[sub * 128 + o], p.out_w[o * 128 + k], acc);
        g_Wf1T[k * 128 + f] = acc;
        red[tid] = rowbuf[sub * 128 + k] * p.out_b[k];
        __syncthreads();
        for (int s = 64; s > 0; s >>= 1) {
            if (k < s) red[tid] += red[tid + s];
            __syncthreads();
        }
        if (k == 0) g_bf1[f] = red[sub * 128] + p.ff_b1[f];
    } else {                                    // fold2: M2=Wfc*W2, b2'=Wfc*b2+bfc
        float* rowbuf = smem; float* red = smem + 256;
        int sub = tid >> 7, k = tid & 127;
        int o = (u - 936) * 2 + sub;
        rowbuf[sub * 128 + k] = (o < 80) ? p.fc_w[o * 128 + k] : 0.f;
        __syncthreads();
        float acc = 0.f;
#pragma unroll 8
        for (int d = 0; d < 128; d++)
            acc = fmaf(rowbuf[sub * 128 + d], p.ff_w2[d * 128 + k], acc);
        g_WfcT[k * 128 + o] = acc;
        red[tid] = rowbuf[sub * 128 + k] * p.ff_b2[k];
        __syncthreads();
        for (int s = 64; s > 0; s >>= 1) {
            if (k < s) red[tid] += red[tid + s];
            __syncthreads();
        }
        if (k == 0) g_bfc[o] = (o < 80) ? (red[sub * 128] + p.fc_b[o]) : 0.f;
    }
}

// ---------------------------------------------------------------------------
// GEMM tile: BM=64 tokens x BN cols, 256 thr as 16x16, TM=4 x TN=BN/16.
// EPI: 0 none, 1 relu, 2 conv(relu+bn+pos), 4 fc row-major [t][80]
// ---------------------------------------------------------------------------
template <int K, int BK, int BN, int LDW, int EPI>
__device__ void gemm_tile(float* smem, const float* __restrict__ X,
                          const float* __restrict__ Wt,
                          const float* __restrict__ bias,
                          const float* __restrict__ bg, const float* __restrict__ bb,
                          const float* __restrict__ brm, const float* __restrict__ brv,
                          float* __restrict__ Y, int tx, int cy, int tid) {
    constexpr int TN = BN / 16;
    float* Xs = smem;                 // [BK][64]
    float* Ws = smem + BK * 64;       // [BK][BN]
    int t0 = tx * 64, cb = cy * BN;
    int tc = tid & 15, tr = tid >> 4;
    float acc[4][TN] = {};
    for (int kc = 0; kc < K; kc += BK) {
        for (int i = tid; i < BK * 16; i += 256) {
            int k = i >> 4, f = i & 15;
            *(float4*)&Xs[k * 64 + f * 4] =
                *(const float4*)&X[(size_t)(kc + k) * LDX + t0 + f * 4];
        }
        for (int i = tid; i < BK * (BN / 4); i += 256) {
            int k = i / (BN / 4), f = i - k * (BN / 4);
            *(float4*)&Ws[k * BN + f * 4] =
                *(const float4*)&Wt[(size_t)(kc + k) * LDW + cb + f * 4];
        }
        __syncthreads();
#pragma unroll 4
        for (int k = 0; k < BK; ++k) {
            float4 a = *(float4*)&Xs[k * 64 + tr * 4];
            float av[4] = {a.x, a.y, a.z, a.w};
            float wv[TN];
            if (TN == 4) {
                float4 w = *(float4*)&Ws[k * BN + tc * 4];
                wv[0] = w.x; wv[1] = w.y; wv[2] = w.z; wv[3] = w.w;
            } else {
#pragma unroll
                for (int j = 0; j < TN; j++) wv[j] = Ws[k * BN + tc * TN + j];
            }
#pragma unroll
            for (int i = 0; i < 4; i++)
#pragma unroll
                for (int j = 0; j < TN; j++)
                    acc[i][j] = fmaf(av[i], wv[j], acc[i][j]);
        }
        __syncthreads();
    }
    if (EPI == 4) {                             // row-major [t][80]
#pragma unroll
        for (int j = 0; j < TN; j++) {
            int c = cb + tc * TN + j;
            if (c < 80) {
                float bv = bias[c];
#pragma unroll
                for (int i = 0; i < 4; i++)
                    Y[(size_t)(t0 + tr * 4 + i) * 80 + c] = acc[i][j] + bv;
            }
        }
    } else {
#pragma unroll
        for (int j = 0; j < TN; j++) {
            int c = cb + tc * TN + j;
            float bv = bias[c];
            float vs[4];
#pragma unroll
            for (int i = 0; i < 4; i++) {
                float v = acc[i][j] + bv;
                if (EPI == 1) v = fmaxf(v, 0.0f);
                if (EPI == 2) {
                    v = fmaxf(v, 0.0f);
                    v = (v - brm[c]) * (bg[c] * rsqrtf(brv[c] + 1e-5f)) + bb[c];
                    v += g_posT[c * L_ + ((t0 & 2047) + tr * 4 + i)];
                }
                vs[i] = v;
            }
            *(float4*)&Y[(size_t)c * LDX + t0 + tr * 4] = *(float4*)vs;
        }
    }
}

// ---------------------------------------------------------------------------
// Attention stage: bid -> (bh, qtile of 512 q, half). 256 thr, 2 adjacent q.
// Parity-split float4 K/V staging (conflict-free ds_read_b128 inner loop).
// half 0: keys [q-64, q) ; half 1: keys (q, q+64]. Partials to g_pA/g_pl.
// ---------------------------------------------------------------------------
__device__ void attn_stage(float* smem, int bid, int tid) {
    int bh = bid >> 3, sub = bid & 7;
    int qt = sub >> 1, hf = sub & 1;
    int qb = qt * 512;
    int b = bh >> 4, h = bh & 15;
    int tb = b * L_;
    int jbase = hf ? (qb + 1) : (qb - 64);
    float4* SK = (float4*)smem;                 // [2][2][288]
    float4* SV = SK + 1152;

    for (int c16 = 0; c16 < 16; c16++) {        // stage 16 ch x 575 slots
        int d = c16 & 7;
        int ch = ((c16 < 8) ? D_ : 2 * D_) + h * 8 + d;
        const float* src = g_qkv + (size_t)ch * LDX + tb;
        float4* base4 = ((c16 < 8) ? SK : SV) + (d >> 2) * 288;
        for (int s = tid; s < 575; s += 256) {
            int j = jbase + s;
            float v = ((unsigned)j < (unsigned)L_) ? src[j] : 0.f;
            ((float*)(base4 + (s & 1) * 576 + (s >> 1)))[d & 3] = v;
        }
    }
    __syncthreads();

    const float sc = 0.35355339059327373f;      // 1/sqrt(8)
    int q0 = qb + 2 * tid;
    float qa[8], qc[8];
#pragma unroll
    for (int d = 0; d < 8; d++) {
        qa[d] = g_qkv[(size_t)(h * 8 + d) * LDX + tb + q0] * sc;
        qc[d] = g_qkv[(size_t)(h * 8 + d) * LDX + tb + q0 + 1] * sc;
    }
    float l0 = 0.f, l1 = 0.f;
    float A0[8] = {}, A1[8] = {};
    int j00 = jbase + 2 * tid;

#pragma unroll 1
    for (int it = 0; it <= 64; it++) {
        int pp = it & 1, idx = tid + (it >> 1);
        float4 ka = SK[pp * 576 + idx], kb2 = SK[pp * 576 + 288 + idx];
        float kv[8] = {ka.x, ka.y, ka.z, ka.w, kb2.x, kb2.y, kb2.z, kb2.w};
        float s0 = 0.f, s1 = 0.f;
#pragma unroll
        for (int d = 0; d < 8; d++) {
            s0 = fmaf(qa[d], kv[d], s0);
            s1 = fmaf(qc[d], kv[d], s1);
        }
        bool jv = (unsigned)(j00 + it) < (unsigned)L_;
        float w0 = (jv && it <= 63) ? __expf(s0) : 0.f;
        float w1 = (jv && it >= 1)  ? __expf(s1) : 0.f;
        l0 += w0; l1 += w1;
        float4 va = SV[pp * 576 + idx], vb2 = SV[pp * 576 + 288 + idx];
        float vv[8] = {va.x, va.y, va.z, va.w, vb2.x, vb2.y, vb2.z, vb2.w};
#pragma unroll
        for (int d = 0; d < 8; d++) {
            A0[d] = fmaf(w0, vv[d], A0[d]);
            A1[d] = fmaf(w1, vv[d], A1[d]);
        }
    }
    int base = bh * L_ + q0;
#pragma unroll
    for (int d = 0; d < 8; d++) {
        g_pA[(size_t)(hf * 8 + d) * BHL + base]     = A0[d];
        g_pA[(size_t)(hf * 8 + d) * BHL + base + 1] = A1[d];
    }
    g_pl[hf * BHL + base]     = l0;
    g_pl[hf * BHL + base + 1] = l1;
}

__device__ void combine_unit(int bid, int tid) {
    int gq = bid * 256 + tid;                   // [0, 131072)
    int bh = gq >> 11, l = gq & 2047;
    int b = bh >> 4, h = bh & 15;
    float inv = 1.f / (g_pl[gq] + g_pl[BHL + gq]);
#pragma unroll
    for (int d = 0; d < 8; d++) {
        float v = (g_pA[(size_t)d * BHL + gq] + g_pA[(size_t)(8 + d) * BHL + gq]) * inv;
        g_ctx[(size_t)(h * 8 + d) * LDX + b * L_ + l] = v;
    }
}

// ---------------------------------------------------------------------------
// Megakernel: 512 blocks x 256 threads, cooperative, 6 grid syncs.
// ---------------------------------------------------------------------------
__global__ __launch_bounds__(256, 2) void mega_kernel(Params p) {
    cg::grid_group grid = cg::this_grid();
    __shared__ float smem[9216];                // 36 KB (max stage: attn)
    int bid = blockIdx.x, tid = threadIdx.x;

    // S0: prep
    for (int u = bid; u < 1000; u += 512) {
        prep_unit(u, tid, p, smem);
        __syncthreads();
    }
    grid.sync();

    // S1: conv+relu+bn+pos  (512 tiles, BN=32)
    gemm_tile<80, 80, 32, 128, 2>(smem, g_xT, g_WconvT, p.conv_b,
                                  p.bn_g, p.bn_b, p.bn_rm, p.bn_rv,
                                  g_h, bid & 127, bid >> 7, tid);
    grid.sync();

    // S2: qkv (768 tiles, BN=64, col-major out)
    for (int u = bid; u < 768; u += 512)
        gemm_tile<128, 64, 64, 384, 0>(smem, g_h, g_WqkvT, p.in_proj_b,
                                       nullptr, nullptr, nullptr, nullptr,
                                       g_qkv, u & 127, u >> 7, tid);
    grid.sync();

    // S3: attention halves
    attn_stage(smem, bid, tid);
    grid.sync();

    // S4: combine -> ctx
    combine_unit(bid, tid);
    grid.sync();

    // S5: fused out_proj+ff1 (256 tiles, BN=64)
    if (bid < 256)
        gemm_tile<128, 64, 64, 128, 1>(smem, g_ctx, g_Wf1T, g_bf1,
                                       nullptr, nullptr, nullptr, nullptr,
                                       g_f1, bid & 127, bid >> 7, tid);
    grid.sync();

    // S6: fused ff2+fc -> row-major [t][80]
    if (bid < 256)
        gemm_tile<128, 64, 64, 128, 4>(smem, g_f1, g_WfcT, g_bfc,
                                       nullptr, nullptr, nullptr, nullptr,
                                       p.out, bid & 127, bid >> 7, tid);
}

// ---------------------------------------------------------------------------
extern "C" void kernel_launch(void* const* d_in, const int* in_sizes, int n_in,
                              void* d_out, int out_size, void* d_ws, size_t ws_size,
                              hipStream_t stream) {
    Params hp;
    hp.x         = (const float*)d_in[0];
    hp.conv_w    = (const float*)d_in[1];
    hp.conv_b    = (const float*)d_in[2];
    hp.bn_g      = (const float*)d_in[3];
    hp.bn_b      = (const float*)d_in[4];
    hp.bn_rm     = (const float*)d_in[5];
    hp.bn_rv     = (const float*)d_in[6];
    hp.in_proj_w = (const float*)d_in[7];
    hp.in_proj_b = (const float*)d_in[8];
    hp.out_w     = (const float*)d_in[9];
    hp.out_b     = (const float*)d_in[10];
    hp.ff_w1     = (const float*)d_in[11];
    hp.ff_b1     = (const float*)d_in[12];
    hp.ff_w2     = (const float*)d_in[13];
    hp.ff_b2     = (const float*)d_in[14];
    hp.fc_w      = (const float*)d_in[15];
    hp.fc_b      = (const float*)d_in[16];
    hp.out       = (float*)d_out;

    void* kargs[] = {(void*)&hp};
    hipLaunchCooperativeKernel((const void*)mega_kernel, dim3(512), dim3(256),
                               kargs, 0, stream);
}

// Round 8
// 167.608 us; speedup vs baseline: 3.3546x; 3.3546x over previous
//
#include <hip/hip_runtime.h>
#include <math.h>

constexpr int B_ = 4, L_ = 2048, DIN = 80, D_ = 128, H_ = 16, DH = 8;
constexpr int T_ = B_ * L_;
constexpr int LDX = T_;              // col-major activations act[chan][token]

// ---- static device globals ----
__device__ float g_xT  [DIN * T_];          // [80][8192]
__device__ float g_posT[D_ * L_];           // [128][2048]
__device__ float g_h   [D_ * T_];           // col-major
__device__ float g_qkv [3 * D_ * T_];       // col-major [384][8192]
__device__ float g_ctx [D_ * T_];
__device__ float g_f1  [D_ * T_];
__device__ float g_WconvT[DIN * D_];        // [k][o]
__device__ float g_WqkvT [D_ * 3 * D_];     // [128][384]
__device__ float g_Wf1T  [D_ * D_];         // fused (W1*Wo)^T  [d][f]
__device__ float g_WfcT  [D_ * D_];         // fused (Wfc*W2)^T [f][o], o>=80 zero
__device__ float g_bf1   [D_];
__device__ float g_bfc   [D_];

// ---------------------------------------------------------------------------
// prep: xT LDS-tile transpose | fp32 posenc | weight transposes | folds
// grid 1000 x 256  (verbatim round-6, proven)
// ---------------------------------------------------------------------------
__global__ __launch_bounds__(256) void prep_kernel(
        const float* __restrict__ x,
        const float* __restrict__ conv_w,
        const float* __restrict__ in_proj_w,
        const float* __restrict__ out_w,  const float* __restrict__ out_b,
        const float* __restrict__ ff_w1,  const float* __restrict__ ff_b1,
        const float* __restrict__ ff_w2,  const float* __restrict__ ff_b2,
        const float* __restrict__ fc_w,   const float* __restrict__ fc_b) {
    __shared__ float smem[80 * 65];
    int bid = blockIdx.x, tid = threadIdx.x;

    if (bid < 128) {                           // x [8192][80] -> xT [80][8192]
        int t0 = bid * 64;
        for (int i = tid; i < 64 * 80; i += 256) {
            int t = i / 80, k = i - t * 80;
            smem[k * 65 + t] = x[(size_t)t0 * 80 + i];
        }
        __syncthreads();
        for (int i = tid; i < 80 * 64; i += 256) {
            int k = i >> 6, tt = i & 63;
            g_xT[(size_t)k * T_ + t0 + tt] = smem[k * 65 + tt];
        }
        return;
    }
    if (bid < 640) {                           // posenc fp32
        int idx = (bid - 128) * 256 + tid;     // [0, 131072)
        int l = idx >> 6, j = idx & 63;
        float inv = __expf((float)j * (-9.210340371976184f / 128.0f));
        float ang = (float)l * inv;
        g_posT[(2 * j) * L_ + l]     = sinf(ang);
        g_posT[(2 * j + 1) * L_ + l] = cosf(ang);
        return;
    }
    if (bid < 680) {                           // conv_w [128][80] -> [80][128]
        int e = (bid - 640) * 256 + tid;
        int o = e / 80, k = e - o * 80;
        g_WconvT[k * D_ + o] = conv_w[e];
        return;
    }
    if (bid < 872) {                           // in_proj_w [384][128] -> [128][384]
        int e = (bid - 680) * 256 + tid;
        int o = e >> 7, k = e & 127;
        g_WqkvT[k * (3 * D_) + o] = in_proj_w[e];
        return;
    }
    float* rowbuf = smem;                      // [2][128]
    float* red = smem + 256;                   // [256]
    if (bid < 936) {                           // fold1: M1=W1*Wo, b1'=W1*bo+b1
        int sub = tid >> 7, k = tid & 127;
        int f = (bid - 872) * 2 + sub;
        rowbuf[sub * 128 + k] = ff_w1[f * 128 + k];
        __syncthreads();
        float acc = 0.f;
#pragma unroll 8
        for (int o = 0; o < 128; o++)
            acc = fmaf(rowbuf[sub * 128 + o], out_w[o * 128 + k], acc);
        g_Wf1T[k * 128 + f] = acc;
        red[tid] = rowbuf[sub * 128 + k] * out_b[k];
        __syncthreads();
        for (int s = 64; s > 0; s >>= 1) {
            if (k < s) red[tid] += red[tid + s];
            __syncthreads();
        }
        if (k == 0) g_bf1[f] = red[sub * 128] + ff_b1[f];
        return;
    }
    {                                          // fold2: M2=Wfc*W2, b2'=Wfc*b2+bfc
        int sub = tid >> 7, k = tid & 127;
        int o = (bid - 936) * 2 + sub;
        rowbuf[sub * 128 + k] = (o < 80) ? fc_w[o * 128 + k] : 0.f;
        __syncthreads();
        float acc = 0.f;
#pragma unroll 8
        for (int d = 0; d < 128; d++)
            acc = fmaf(rowbuf[sub * 128 + d], ff_w2[d * 128 + k], acc);
        g_WfcT[k * 128 + o] = acc;
        red[tid] = rowbuf[sub * 128 + k] * ff_b2[k];
        __syncthreads();
        for (int s = 64; s > 0; s >>= 1) {
            if (k < s) red[tid] += red[tid + s];
            __syncthreads();
        }
        if (k == 0) g_bfc[o] = (o < 80) ? (red[sub * 128] + fc_b[o]) : 0.f;
        return;
    }
}

// ---------------------------------------------------------------------------
// GEMM (verbatim round-6, proven): BM=64 x BN, 256 thr 16x16, TM=4 x TN=BN/16.
// EPI: 0 none, 1 relu, 2 conv(relu+bn+pos), 4 fc row-major [t][80]
// ---------------------------------------------------------------------------
template <int K, int BK, int BN, int LDW, int EPI>
__global__ __launch_bounds__(256) void gemm_kernel(
        const float* __restrict__ X, const float* __restrict__ Wt,
        const float* __restrict__ bias,
        const float* __restrict__ bg, const float* __restrict__ bb,
        const float* __restrict__ brm, const float* __restrict__ brv,
        float* __restrict__ Y) {
    constexpr int TN = BN / 16;
    __shared__ float Xs[BK][64];
    __shared__ float Ws[BK][BN];
    int tid = threadIdx.x;
    int t0 = blockIdx.x * 64;
    int cb = blockIdx.y * BN;
    int tc = tid & 15, tr = tid >> 4;

    float acc[4][TN] = {};
    for (int kc = 0; kc < K; kc += BK) {
        for (int i = tid; i < BK * 16; i += 256) {
            int k = i >> 4, f = i & 15;
            *(float4*)&Xs[k][f * 4] =
                *(const float4*)&X[(size_t)(kc + k) * LDX + t0 + f * 4];
        }
        for (int i = tid; i < BK * (BN / 4); i += 256) {
            int k = i / (BN / 4), f = i - k * (BN / 4);
            *(float4*)&Ws[k][f * 4] =
                *(const float4*)&Wt[(size_t)(kc + k) * LDW + cb + f * 4];
        }
        __syncthreads();
#pragma unroll 4
        for (int k = 0; k < BK; ++k) {
            float4 a = *(float4*)&Xs[k][tr * 4];
            float av[4] = {a.x, a.y, a.z, a.w};
            float wv[TN];
#pragma unroll
            for (int jj = 0; jj < TN; jj++) wv[jj] = Ws[k][tc * TN + jj];
#pragma unroll
            for (int i = 0; i < 4; i++)
#pragma unroll
                for (int jj = 0; jj < TN; jj++)
                    acc[i][jj] = fmaf(av[i], wv[jj], acc[i][jj]);
        }
        __syncthreads();
    }

    if (EPI == 4) {                            // row-major [t][80]
#pragma unroll
        for (int jj = 0; jj < TN; jj++) {
            int c = cb + tc * TN + jj;
            if (c < 80) {
                float bv = bias[c];
#pragma unroll
                for (int i = 0; i < 4; i++) {
                    int t = t0 + tr * 4 + i;
                    Y[(size_t)t * 80 + c] = acc[i][jj] + bv;
                }
            }
        }
        return;
    }
#pragma unroll
    for (int jj = 0; jj < TN; jj++) {
        int c = cb + tc * TN + jj;
        float bv = bias[c];
        float vs[4];
#pragma unroll
        for (int i = 0; i < 4; i++) {
            float v = acc[i][jj] + bv;
            if (EPI == 1) v = fmaxf(v, 0.0f);
            if (EPI == 2) {
                v = fmaxf(v, 0.0f);
                v = (v - brm[c]) * (bg[c] * rsqrtf(brv[c] + 1e-5f)) + bb[c];
                v += g_posT[c * L_ + ((t0 & 2047) + tr * 4 + i)];
            }
            vs[i] = v;
        }
        *(float4*)&Y[(size_t)c * LDX + t0 + tr * 4] = *(float4*)vs;
    }
}

// ---------------------------------------------------------------------------
// Attention, full-window fused (replaces split-halves + combine).
// Block = (bh, 512-q tile), 256 thr, 2 adjacent q/thread. Window 641 slots
// staged once, parity-split float4 (conflict-free ds_read_b128 inner loop).
// it in [0,129]; q0 valid: it!=64 && it<=128; q1 valid: it!=65 && it>=1.
// Writes normalized ctx directly (col-major, coalesced).
// ---------------------------------------------------------------------------
__global__ __launch_bounds__(256) void attn_kernel() {
    __shared__ float4 SK[2][2][324];            // [parity][dhalf][idx]
    __shared__ float4 SV[2][2][324];
    int bh = blockIdx.x;                        // 64
    int qb = blockIdx.y * 512;                  // 4 tiles
    int b = bh >> 4, h = bh & 15;
    int tb = b * L_;
    int tid = threadIdx.x;
    int jbase = qb - 64;

    for (int c16 = 0; c16 < 16; c16++) {        // stage 16 ch x 641 slots
        int d = c16 & 7;
        int ch = ((c16 < 8) ? D_ : 2 * D_) + h * 8 + d;
        const float* src = g_qkv + (size_t)ch * LDX + tb;
        float4* base4 = ((c16 < 8) ? &SK[0][0][0] : &SV[0][0][0]) + (d >> 2) * 324;
        for (int s = tid; s < 641; s += 256) {
            int j = jbase + s;
            float v = ((unsigned)j < (unsigned)L_) ? src[j] : 0.f;
            ((float*)(base4 + (s & 1) * 648 + (s >> 1)))[d & 3] = v;
        }
    }
    __syncthreads();

    const float sc = 0.35355339059327373f;      // 1/sqrt(8)
    int q0 = qb + 2 * tid;
    float qa[8], qc[8];
#pragma unroll
    for (int d = 0; d < 8; d++) {
        qa[d] = g_qkv[(size_t)(h * 8 + d) * LDX + tb + q0] * sc;
        qc[d] = g_qkv[(size_t)(h * 8 + d) * LDX + tb + q0 + 1] * sc;
    }
    float l0 = 0.f, l1 = 0.f;
    float A0[8] = {}, A1[8] = {};
    int j00 = jbase + 2 * tid;

#pragma unroll 2
    for (int it = 0; it <= 129; it++) {
        int pp = it & 1, idx = tid + (it >> 1);
        float4 ka = SK[pp][0][idx], kb2 = SK[pp][1][idx];
        float kv[8] = {ka.x, ka.y, ka.z, ka.w, kb2.x, kb2.y, kb2.z, kb2.w};
        float s0 = 0.f, s1 = 0.f;
#pragma unroll
        for (int d = 0; d < 8; d++) {
            s0 = fmaf(qa[d], kv[d], s0);
            s1 = fmaf(qc[d], kv[d], s1);
        }
        bool jv = (unsigned)(j00 + it) < (unsigned)L_;
        float w0 = (jv && it != 64 && it <= 128) ? __expf(s0) : 0.f;
        float w1 = (jv && it != 65 && it >= 1)  ? __expf(s1) : 0.f;
        l0 += w0; l1 += w1;
        float4 va = SV[pp][0][idx], vb2 = SV[pp][1][idx];
        float vv[8] = {va.x, va.y, va.z, va.w, vb2.x, vb2.y, vb2.z, vb2.w};
#pragma unroll
        for (int d = 0; d < 8; d++) {
            A0[d] = fmaf(w0, vv[d], A0[d]);
            A1[d] = fmaf(w1, vv[d], A1[d]);
        }
    }
    float i0 = 1.f / l0, i1 = 1.f / l1;
    int base = tb + q0;
#pragma unroll
    for (int d = 0; d < 8; d++) {               // col-major ctx
        g_ctx[(size_t)(h * 8 + d) * LDX + base]     = A0[d] * i0;
        g_ctx[(size_t)(h * 8 + d) * LDX + base + 1] = A1[d] * i1;
    }
}

// ---------------------------------------------------------------------------
extern "C" void kernel_launch(void* const* d_in, const int* in_sizes, int n_in,
                              void* d_out, int out_size, void* d_ws, size_t ws_size,
                              hipStream_t stream) {
    const float* x         = (const float*)d_in[0];
    const float* conv_w    = (const float*)d_in[1];
    const float* conv_b    = (const float*)d_in[2];
    const float* bn_g      = (const float*)d_in[3];
    const float* bn_b      = (const float*)d_in[4];
    const float* bn_rm     = (const float*)d_in[5];
    const float* bn_rv     = (const float*)d_in[6];
    const float* in_proj_w = (const float*)d_in[7];
    const float* in_proj_b = (const float*)d_in[8];
    const float* out_w     = (const float*)d_in[9];
    const float* out_b     = (const float*)d_in[10];
    const float* ff_w1     = (const float*)d_in[11];
    const float* ff_b1     = (const float*)d_in[12];
    const float* ff_w2     = (const float*)d_in[13];
    const float* ff_b2     = (const float*)d_in[14];
    const float* fc_w      = (const float*)d_in[15];
    const float* fc_b      = (const float*)d_in[16];

    float *p_xT, *p_h, *p_qkv, *p_ctx, *p_f1;
    float *p_WconvT, *p_WqkvT, *p_Wf1T, *p_WfcT, *p_bf1, *p_bfc;
    hipGetSymbolAddress((void**)&p_xT,     HIP_SYMBOL(g_xT));
    hipGetSymbolAddress((void**)&p_h,      HIP_SYMBOL(g_h));
    hipGetSymbolAddress((void**)&p_qkv,    HIP_SYMBOL(g_qkv));
    hipGetSymbolAddress((void**)&p_ctx,    HIP_SYMBOL(g_ctx));
    hipGetSymbolAddress((void**)&p_f1,     HIP_SYMBOL(g_f1));
    hipGetSymbolAddress((void**)&p_WconvT, HIP_SYMBOL(g_WconvT));
    hipGetSymbolAddress((void**)&p_WqkvT,  HIP_SYMBOL(g_WqkvT));
    hipGetSymbolAddress((void**)&p_Wf1T,   HIP_SYMBOL(g_Wf1T));
    hipGetSymbolAddress((void**)&p_WfcT,   HIP_SYMBOL(g_WfcT));
    hipGetSymbolAddress((void**)&p_bf1,    HIP_SYMBOL(g_bf1));
    hipGetSymbolAddress((void**)&p_bfc,    HIP_SYMBOL(g_bfc));

    prep_kernel<<<1000, 256, 0, stream>>>(x, conv_w, in_proj_w, out_w, out_b,
                                          ff_w1, ff_b1, ff_w2, ff_b2, fc_w, fc_b);

    // conv+relu+bn+pos: K=80 single chunk, BN=32, 512 blocks
    gemm_kernel<80, 80, 32, 128, 2><<<dim3(128, 4), 256, 0, stream>>>(
        p_xT, p_WconvT, conv_b, bn_g, bn_b, bn_rm, bn_rv, p_h);

    // qkv: K=128 BK=64, BN=64, col-major out, 768 blocks
    gemm_kernel<128, 64, 64, 384, 0><<<dim3(128, 6), 256, 0, stream>>>(
        p_h, p_WqkvT, in_proj_b, nullptr, nullptr, nullptr, nullptr, p_qkv);

    // fused full-window attention -> ctx (256 blocks)
    attn_kernel<<<dim3(64, 4), 256, 0, stream>>>();

    // fused out_proj+ff1: relu(ctx*M1^T + b1'), 512 blocks
    gemm_kernel<128, 128, 32, 128, 1><<<dim3(128, 4), 256, 0, stream>>>(
        p_ctx, p_Wf1T, p_bf1, nullptr, nullptr, nullptr, nullptr, p_f1);

    // fused ff2+fc -> row-major [t][80], 384 blocks
    gemm_kernel<128, 128, 32, 128, 4><<<dim3(128, 3), 256, 0, stream>>>(
        p_f1, p_WfcT, p_bfc, nullptr, nullptr, nullptr, nullptr, (float*)d_out);
}